// Round 1
// baseline (87.675 us; speedup 1.0000x reference)
//
#include <hip/hip_runtime.h>

// SE3Transform: out_pos[m*N+n] = R[batch[n]+16m] @ xyz[n] + p[batch[n]+16m]
//               out_batch[m*N+n] = batch[n] + 16m  (written as float)
// N=500000, B=16, M=8, trans=[128,4,4] f32.
// Write-BW-bound: 64MB stores + 8MB loads => ~11.4us floor @6.3TB/s.

#define N_POINTS 500000
#define N_BATCH  16
#define M_TRANS  8
#define NT       128          // M_TRANS * N_BATCH
#define TSTRIDE  20           // dword stride per trans slot in LDS (bank spread; 16B-aligned rows)

__global__ __launch_bounds__(256) void se3_kernel(
    const float* __restrict__ trans,   // [128,4,4]
    const float* __restrict__ xyz,     // [N,3]
    const int*   __restrict__ batch,   // [N]
    float* __restrict__ out)           // [12M pos floats][4M batch floats]
{
    __shared__ float s_trans[NT * TSTRIDE];   // 10,240 B

    // Stage trans -> LDS. 512 float4s, 256 threads -> 2 each.
    for (int i = threadIdx.x; i < NT * 4; i += 256) {
        int pt  = i >> 2;          // which 4x4 matrix
        int row = i & 3;           // which row
        float4 v = ((const float4*)trans)[i];
        *(float4*)&s_trans[pt * TSTRIDE + row * 4] = v;
    }
    __syncthreads();

    int g  = blockIdx.x * 256 + threadIdx.x;  // group of 4 points
    int n0 = g * 4;
    if (n0 >= N_POINTS) return;               // N divisible by 4: full groups only

    // 4 batch indices (16B coalesced)
    int4 b4 = ((const int4*)batch)[g];
    int bi[4] = {b4.x, b4.y, b4.z, b4.w};

    // 12 xyz floats as 3x float4 (contiguous 48B per thread)
    float4 x0 = ((const float4*)xyz)[g * 3 + 0];
    float4 x1 = ((const float4*)xyz)[g * 3 + 1];
    float4 x2 = ((const float4*)xyz)[g * 3 + 2];
    float px[4] = {x0.x, x0.w, x1.z, x2.y};
    float py[4] = {x0.y, x1.x, x1.w, x2.z};
    float pz[4] = {x0.z, x1.y, x2.x, x2.w};

    float* out_pos   = out;                       // 12,000,000 floats
    float* out_batch = out + 12000000;            // 4,000,000 floats

    #pragma unroll
    for (int m = 0; m < M_TRANS; ++m) {
        float o[12];
        float nbf[4];
        #pragma unroll
        for (int j = 0; j < 4; ++j) {
            int nb = bi[j] + m * N_BATCH;
            nbf[j] = (float)nb;
            const float* T = &s_trans[nb * TSTRIDE];
            float4 r0 = *(const float4*)(T + 0);   // R00 R01 R02 p0
            float4 r1 = *(const float4*)(T + 4);   // R10 R11 R12 p1
            float4 r2 = *(const float4*)(T + 8);   // R20 R21 R22 p2
            o[j * 3 + 0] = fmaf(r0.x, px[j], fmaf(r0.y, py[j], fmaf(r0.z, pz[j], r0.w)));
            o[j * 3 + 1] = fmaf(r1.x, px[j], fmaf(r1.y, py[j], fmaf(r1.z, pz[j], r1.w)));
            o[j * 3 + 2] = fmaf(r2.x, px[j], fmaf(r2.y, py[j], fmaf(r2.z, pz[j], r2.w)));
        }
        // pos stores: base + m*1,500,000 + 12g floats -- all offsets 16B-aligned
        float* dst = out_pos + (size_t)m * (N_POINTS * 3) + (size_t)n0 * 3;
        ((float4*)dst)[0] = make_float4(o[0], o[1], o[2],  o[3]);
        ((float4*)dst)[1] = make_float4(o[4], o[5], o[6],  o[7]);
        ((float4*)dst)[2] = make_float4(o[8], o[9], o[10], o[11]);
        // batch store: base + m*500,000 + 4g floats -- 16B-aligned
        float* bdst = out_batch + (size_t)m * N_POINTS + n0;
        *(float4*)bdst = make_float4(nbf[0], nbf[1], nbf[2], nbf[3]);
    }
}

extern "C" void kernel_launch(void* const* d_in, const int* in_sizes, int n_in,
                              void* d_out, int out_size, void* d_ws, size_t ws_size,
                              hipStream_t stream) {
    const float* trans = (const float*)d_in[0];   // 2048 floats
    const float* xyz   = (const float*)d_in[1];   // 1,500,000 floats
    const int*   batch = (const int*)d_in[2];     // 500,000 ints
    float* out = (float*)d_out;                   // 16,000,000 floats

    const int groups = N_POINTS / 4;              // 125,000
    const int block  = 256;
    const int grid   = (groups + block - 1) / block;  // 489
    se3_kernel<<<grid, block, 0, stream>>>(trans, xyz, batch, out);
}

// Round 2
// 82.780 us; speedup vs baseline: 1.0591x; 1.0591x over previous
//
#include <hip/hip_runtime.h>

// SE3Transform: out_pos[m*N+n] = R[batch[n]+16m] @ xyz[n] + p[batch[n]+16m]
//               out_batch[m*N+n] = batch[n] + 16m  (as float)
// N=500000, B=16, M=8, trans=[128,4,4] f32.
// Write-BW-bound: 64MB stores + 8MB loads => ~11.4us kernel floor @6.3TB/s.
// R1 lesson: 48B-stride float4 stores cost ~3x transaction slots (43us).
// Fix: wave-local LDS transpose -> lane-contiguous float4 stores.

#define N_POINTS     500000
#define N_GROUPS     125000     // N_POINTS/4
#define N_BATCH      16
#define M_TRANS      8
#define NT           128        // M_TRANS * N_BATCH
#define TSTRIDE      20         // dword stride per matrix in LDS (bank spread)
#define POS_F4_PER_M 375000     // 1.5M floats / 4 per m-slice

__global__ __launch_bounds__(256) void se3_kernel(
    const float* __restrict__ trans,   // [128,4,4]
    const float* __restrict__ xyz,     // [N,3]
    const int*   __restrict__ batch,   // [N]
    float* __restrict__ out)           // [12M pos floats][4M batch floats]
{
    __shared__ float s_trans[NT * TSTRIDE];     // 10,240 B
    __shared__ float s_stage[4][64 * 12];       // 4 waves x 3 KB

    // Stage trans -> LDS (512 float4s, 2 per thread).
    for (int i = threadIdx.x; i < NT * 4; i += 256) {
        int pt  = i >> 2;
        int row = i & 3;
        float4 v = ((const float4*)trans)[i];
        *(float4*)&s_trans[pt * TSTRIDE + row * 4] = v;
    }
    __syncthreads();

    const int lane = threadIdx.x & 63;
    const int wave = threadIdx.x >> 6;
    const int g    = blockIdx.x * 256 + threadIdx.x;   // group of 4 points
    const bool active = (g < N_GROUPS);

    const int wg0       = blockIdx.x * 256 + wave * 64;  // wave's first group
    const int region_f4 = wg0 * 3;                       // float4 base of wave's pos region

    int   bi[4];
    float px[4], py[4], pz[4];
    if (active) {
        int4 b4 = ((const int4*)batch)[g];
        bi[0] = b4.x; bi[1] = b4.y; bi[2] = b4.z; bi[3] = b4.w;
        float4 x0 = ((const float4*)xyz)[g * 3 + 0];
        float4 x1 = ((const float4*)xyz)[g * 3 + 1];
        float4 x2 = ((const float4*)xyz)[g * 3 + 2];
        px[0] = x0.x; px[1] = x0.w; px[2] = x1.z; px[3] = x2.y;
        py[0] = x0.y; py[1] = x1.x; py[2] = x1.w; py[3] = x2.z;
        pz[0] = x0.z; pz[1] = x1.y; pz[2] = x2.x; pz[3] = x2.w;
    }

    float*  out_pos   = out;                 // 12,000,000 floats
    float*  out_batch = out + 12000000;      // 4,000,000 floats
    float4* stage     = (float4*)s_stage[wave];

    #pragma unroll
    for (int m = 0; m < M_TRANS; ++m) {
        if (active) {
            float o[12];
            float nbf[4];
            #pragma unroll
            for (int j = 0; j < 4; ++j) {
                int nb = bi[j] + m * N_BATCH;
                nbf[j] = (float)nb;
                const float* T = &s_trans[nb * TSTRIDE];
                float4 r0 = *(const float4*)(T + 0);   // R00 R01 R02 p0
                float4 r1 = *(const float4*)(T + 4);   // R10 R11 R12 p1
                float4 r2 = *(const float4*)(T + 8);   // R20 R21 R22 p2
                o[j * 3 + 0] = fmaf(r0.x, px[j], fmaf(r0.y, py[j], fmaf(r0.z, pz[j], r0.w)));
                o[j * 3 + 1] = fmaf(r1.x, px[j], fmaf(r1.y, py[j], fmaf(r1.z, pz[j], r1.w)));
                o[j * 3 + 2] = fmaf(r2.x, px[j], fmaf(r2.y, py[j], fmaf(r2.z, pz[j], r2.w)));
            }
            // Stage 12 floats (3 float4 chunks) into the wave's LDS region.
            stage[lane * 3 + 0] = make_float4(o[0], o[1], o[2],  o[3]);
            stage[lane * 3 + 1] = make_float4(o[4], o[5], o[6],  o[7]);
            stage[lane * 3 + 2] = make_float4(o[8], o[9], o[10], o[11]);
            // Batch store: lane-contiguous float4 -- already coalesced.
            *(float4*)(out_batch + (size_t)m * N_POINTS + g * 4) =
                make_float4(nbf[0], nbf[1], nbf[2], nbf[3]);
        }
        __builtin_amdgcn_wave_barrier();   // pin ds_write -> ds_read order

        // Coalesced pos stores: lane i stores float4 (64k + i) of the region.
        const int base_m = m * POS_F4_PER_M;
        float4* gdst = (float4*)out_pos + base_m;
        #pragma unroll
        for (int k = 0; k < 3; ++k) {
            int idx = 64 * k + lane;
            if (region_f4 + idx < POS_F4_PER_M)
                gdst[region_f4 + idx] = stage[idx];
        }
        __builtin_amdgcn_wave_barrier();   // pin ds_read -> next ds_write order
    }
}

extern "C" void kernel_launch(void* const* d_in, const int* in_sizes, int n_in,
                              void* d_out, int out_size, void* d_ws, size_t ws_size,
                              hipStream_t stream) {
    const float* trans = (const float*)d_in[0];   // 2048 floats
    const float* xyz   = (const float*)d_in[1];   // 1,500,000 floats
    const int*   batch = (const int*)d_in[2];     // 500,000 ints
    float* out = (float*)d_out;                   // 16,000,000 floats

    const int block = 256;
    const int grid  = (N_GROUPS + block - 1) / block;  // 489
    se3_kernel<<<grid, block, 0, stream>>>(trans, xyz, batch, out);
}

// Round 3
// 82.719 us; speedup vs baseline: 1.0599x; 1.0007x over previous
//
#include <hip/hip_runtime.h>

// SE3Transform: out_pos[m*N+n] = R[batch[n]+16m] @ xyz[n] + p[batch[n]+16m]
//               out_batch[m*N+n] = batch[n] + 16m (as float)
// N=500000, B=16, M=8. Floor: 64MB W + ~10MB R => ~11.4us @6.3TB/s.
//
// R2 lesson: per-m LDS output round-trip serializes 8 iterations (~2400
// unhideable stall cyc/wave). R3: thread <-> output float4 directly.
// Each output float4 (floats 4f..4f+3 of the 1.5M pos stream) needs rows
// c_k=(t3+k)%3 of matrices A=(4f-t3)/3, B=A+1 (t3=f%3). Row offsets into
// s_trans are m-invariant; per m: 4 ds_read_b128 + 12 fma + 1 coalesced
// store_dwordx4. All m-iterations independent -> fully pipelineable.

#define NPTS   500000
#define POSF4  375000     // pos float4s per m-slice
#define BATF4  125000     // batch float4s per m-slice
#define NT     128
#define TSTR   20         // dword stride per matrix in LDS (bank spread)

__global__ __launch_bounds__(256) void se3_kernel(
    const float* __restrict__ trans,   // [128,4,4]
    const float* __restrict__ xyz,     // [N,3]
    const int*   __restrict__ batch,   // [N]
    float* __restrict__ out)           // [12M pos floats][4M batch floats]
{
    __shared__ float  s_t[NT * TSTR];  // 10,240 B
    __shared__ float4 s_x[264];        //  4,224 B: xyz f4 window [F-2, F+262)

    const int tid = threadIdx.x;
    const int F   = blockIdx.x * 256;
    const int t   = F + tid;

    // Stage trans -> LDS (512 f4, 2/thread). Row c of matrix nb at dword
    // nb*20 + c*4 = [Rc0 Rc1 Rc2 pc].
    for (int i = tid; i < NT * 4; i += 256) {
        int pt = i >> 2, row = i & 3;
        float4 v = ((const float4*)trans)[i];
        *(float4*)&s_t[pt * TSTR + row * 4] = v;
    }
    // Stage xyz window for pos blocks (coalesced f4 loads, clamped).
    if (F < POSF4) {
        for (int i = tid; i < 264; i += 256) {
            int idx = F - 2 + i;
            idx = idx < 0 ? 0 : (idx >= POSF4 ? POSF4 - 1 : idx);
            s_x[i] = ((const float4*)xyz)[idx];
        }
    }
    __syncthreads();

    if (t < POSF4) {
        const int f  = t;
        const int t3 = f % 3;
        const int n0 = (4 * f - t3) / 3;         // first point this f4 touches

        // 6 xyz floats [4f-t3 .. 4f-t3+5] from the window.
        const float* sxf = (const float*)s_x;
        const int off = 4 * tid + 8 - t3;
        float xa = sxf[off + 0], xb = sxf[off + 1], xc = sxf[off + 2];
        float xd = sxf[off + 3], xe = sxf[off + 4], xf = sxf[off + 5];

        const int b0 = batch[n0];
        const int b1 = batch[n0 + 1];

        // Per output comp k: c_k=(t3+k)%3, sel_k=(t3+k)/3; m-invariant
        // byte offset into s_t, and the point's xyz comps.
        int   ro[4];
        float X0[4], X1[4], X2[4];
        #pragma unroll
        for (int k = 0; k < 4; ++k) {
            int ck = t3 + k, sel = 0;
            if (ck >= 3) { ck -= 3; sel = 1; }
            int b = sel ? b1 : b0;
            ro[k] = b * (TSTR * 4) + ck * 16;    // bytes
            X0[k] = sel ? xd : xa;
            X1[k] = sel ? xe : xb;
            X2[k] = sel ? xf : xc;
        }

        const char* stb = (const char*)s_t;
        float4* po = (float4*)out;
        #pragma unroll
        for (int m = 0; m < 8; ++m) {
            // m stride = 16 matrices * 20 dwords * 4B = 1280B (imm offset)
            float4 r0 = *(const float4*)(stb + ro[0] + m * 1280);
            float4 r1 = *(const float4*)(stb + ro[1] + m * 1280);
            float4 r2 = *(const float4*)(stb + ro[2] + m * 1280);
            float4 r3 = *(const float4*)(stb + ro[3] + m * 1280);
            float4 v;
            v.x = fmaf(r0.x, X0[0], fmaf(r0.y, X1[0], fmaf(r0.z, X2[0], r0.w)));
            v.y = fmaf(r1.x, X0[1], fmaf(r1.y, X1[1], fmaf(r1.z, X2[1], r1.w)));
            v.z = fmaf(r2.x, X0[2], fmaf(r2.y, X1[2], fmaf(r2.z, X2[2], r2.w)));
            v.w = fmaf(r3.x, X0[3], fmaf(r3.y, X1[3], fmaf(r3.z, X2[3], r3.w)));
            po[m * POSF4 + f] = v;               // lane-contiguous, coalesced
        }
    } else if (t < POSF4 + BATF4) {
        const int q = t - POSF4;
        int4 b4 = ((const int4*)batch)[q];
        float4* ob = (float4*)(out + 12000000);
        #pragma unroll
        for (int m = 0; m < 8; ++m) {
            const int a = m * 16;
            ob[m * BATF4 + q] = make_float4((float)(b4.x + a), (float)(b4.y + a),
                                            (float)(b4.z + a), (float)(b4.w + a));
        }
    }
}

extern "C" void kernel_launch(void* const* d_in, const int* in_sizes, int n_in,
                              void* d_out, int out_size, void* d_ws, size_t ws_size,
                              hipStream_t stream) {
    const float* trans = (const float*)d_in[0];   // 2048 floats
    const float* xyz   = (const float*)d_in[1];   // 1,500,000 floats
    const int*   batch = (const int*)d_in[2];     // 500,000 ints
    float* out = (float*)d_out;                   // 16,000,000 floats

    const int total = POSF4 + BATF4;              // 500,000 work items
    const int block = 256;
    const int grid  = (total + block - 1) / block; // 1954
    se3_kernel<<<grid, block, 0, stream>>>(trans, xyz, batch, out);
}